// Round 6
// baseline (2168.627 us; speedup 1.0000x reference)
//
#include <hip/hip_runtime.h>

#define HH 256
#define WW 256
#define HWSZ (HH*WW)
#define CH 32

__device__ __forceinline__ float lrelu_f(float x){ return x >= 0.f ? x : 0.2f*x; }

// Bijective XCD swizzle (m204): contiguous chunks of blocks per XCD.
__device__ __forceinline__ int xcd_swizzle(int bid, int nwg) {
    const int NX = 8;
    int q = nwg / NX, r = nwg % NX;
    int xcd = bid % NX, idx = bid / NX;
    if (bid >= (nwg / NX) * NX + r) return bid;
    int base = (xcd < r) ? xcd * (q + 1) : r * (q + 1) + (xcd - r) * q;
    return base + idx;
}

// 1x1 conv over concat(short, long): y[b,o,hw] = bias[o] + sum_c w[o][c]*s + w[o][32+c]*l
__global__ __launch_bounds__(256) void conv1x1_kernel(
    const float* __restrict__ s, const float* __restrict__ l,
    const float* __restrict__ w, const float* __restrict__ bias,
    float* __restrict__ y)
{
    int gid = blockIdx.x*256 + threadIdx.x;   // over 2*HWSZ
    int b = gid >> 16;
    int pix = gid & (HWSZ-1);
    const float* sp = s + (size_t)b*CH*HWSZ + pix;
    const float* lp = l + (size_t)b*CH*HWSZ + pix;
    float acc[CH];
    #pragma unroll
    for (int o=0;o<CH;++o) acc[o] = bias[o];
    for (int c=0;c<CH;++c) {
        float v = sp[(size_t)c*HWSZ];
        #pragma unroll
        for (int o=0;o<CH;++o) acc[o] += w[o*64+c]*v;
    }
    for (int c=0;c<CH;++c) {
        float v = lp[(size_t)c*HWSZ];
        #pragma unroll
        for (int o=0;o<CH;++o) acc[o] += w[o*64+32+c]*v;
    }
    float* yp = y + (size_t)b*CH*HWSZ + pix;
    #pragma unroll
    for (int o=0;o<CH;++o) yp[(size_t)o*HWSZ] = acc[o];
}

// 3x3 conv, pad=1, Cout=32, Cin = 32*NP (phase 0 from x0, phase 1 from x1). Optional lrelu.
template<int NP>
__global__ __launch_bounds__(256) void conv3x3_kernel(
    const float* __restrict__ x0, const float* __restrict__ x1,
    const float* __restrict__ w, const float* __restrict__ bias,
    float* __restrict__ y, int relu)
{
    int gid = blockIdx.x*256 + threadIdx.x;   // over 2*HWSZ
    int b = gid >> 16;
    int pix = gid & (HWSZ-1);
    int h = pix >> 8, cw = pix & 255;
    const int CIN = 32*NP;
    float acc[CH];
    #pragma unroll
    for (int o=0;o<CH;++o) acc[o] = bias[o];
    #pragma unroll
    for (int p=0;p<NP;++p) {
        const float* src = (p==0) ? x0 : x1;
        const float* xb = src + (size_t)b*CH*HWSZ;
        for (int c=0;c<CH;++c) {
            const float* xp = xb + (size_t)c*HWSZ;
            float v[9];
            #pragma unroll
            for (int t=0;t<9;++t) {
                int hh = h + t/3 - 1;
                int wx = cw + t%3 - 1;
                v[t] = (hh>=0 && hh<HH && wx>=0 && wx<WW) ? xp[hh*WW+wx] : 0.f;
            }
            const float* wp = w + (size_t)(p*32 + c)*9;   // + o*CIN*9 + t
            #pragma unroll
            for (int o=0;o<CH;++o) {
                #pragma unroll
                for (int t=0;t<9;++t)
                    acc[o] += wp[(size_t)o*CIN*9 + t] * v[t];
            }
        }
    }
    float* yp = y + (size_t)b*CH*HWSZ + pix;
    #pragma unroll
    for (int o=0;o<CH;++o)
        yp[(size_t)o*HWSZ] = relu ? lrelu_f(acc[o]) : acc[o];
}

// bilinear x2 upsample (align_corners=False) of [2,32,128,128] -> [2,32,256,256], times 2.0
__global__ __launch_bounds__(256) void up2_kernel(
    const float* __restrict__ x, float* __restrict__ y)
{
    int gid = blockIdx.x*256 + threadIdx.x;   // over 2*32*256*256
    int ow = gid & 255;
    int oh = (gid >> 8) & 255;
    int bc = gid >> 16;                        // 0..63
    const int Hin = 128, Win = 128;
    float cy = (oh + 0.5f)*0.5f - 0.5f;
    float cx = (ow + 0.5f)*0.5f - 0.5f;
    cy = fminf(fmaxf(cy, 0.f), (float)(Hin-1));
    cx = fminf(fmaxf(cx, 0.f), (float)(Win-1));
    int y0 = (int)floorf(cy);
    int x0 = (int)floorf(cx);
    int y1 = min(y0+1, Hin-1);
    int x1 = min(x0+1, Win-1);
    float ty = cy - (float)y0, tx = cx - (float)x0;
    const float* xp = x + (size_t)bc*Hin*Win;
    float v00 = xp[y0*Win+x0], v01 = xp[y0*Win+x1];
    float v10 = xp[y1*Win+x0], v11 = xp[y1*Win+x1];
    float v = v00*(1.f-ty)*(1.f-tx) + v01*(1.f-ty)*tx + v10*ty*(1.f-tx) + v11*ty*tx;
    y[gid] = 2.0f*v;
}

// 3x3 conv 32 -> 216 (no act). Covers nb batches, rows [r0, r0+rows) of each.
// grid.x = nb*rows (b-major), grid.y = 9 (24 out-chans each).
// om layout per batch: [216][rows][W], batch stride 216*rows*W.
__global__ __launch_bounds__(256) void dcn_off_kernel(
    const float* __restrict__ x,    // off full tensor [nb,32,H,W]
    const float* __restrict__ w,    // [216,32,9]
    const float* __restrict__ bias,
    float* __restrict__ om,
    int r0, int rows)
{
    int b = blockIdx.x / rows;
    int rr = blockIdx.x % rows;
    int cw = threadIdx.x;
    int h = r0 + rr;
    int oc0 = blockIdx.y*24;
    const float* xb = x + (size_t)b*CH*HWSZ;
    float* omb = om + (size_t)b*216*rows*WW;
    float acc[24];
    #pragma unroll
    for (int j=0;j<24;++j) acc[j] = bias[oc0+j];
    for (int c=0;c<32;++c) {
        const float* xp = xb + (size_t)c*HWSZ;
        float v[9];
        #pragma unroll
        for (int t=0;t<9;++t) {
            int hh = h + t/3 - 1;
            int wx = cw + t%3 - 1;
            v[t] = (hh>=0 && hh<HH && wx>=0 && wx<WW) ? xp[hh*WW+wx] : 0.f;
        }
        const float* wp = w + (size_t)c*9;   // + (oc0+j)*288 + t
        #pragma unroll
        for (int j=0;j<24;++j) {
            #pragma unroll
            for (int t=0;t<9;++t)
                acc[j] += wp[(size_t)(oc0+j)*288 + t] * v[t];
        }
    }
    #pragma unroll
    for (int j=0;j<24;++j)
        omb[(size_t)(oc0+j)*rows*WW + (size_t)rr*WW + cw] = acc[j];
}

// DCNv2 sampling + einsum + bias + lrelu.
// Block: 256 threads = 4 waves. Wave `sub` handles `ng` groups starting at
// sub*ng for a 64-pixel tile; LDS tree-reduce combines the 4 partial acc[32].
//
// CRITICAL (R4/R5 post-mortem): the group loop's trip count must be OPAQUE at
// compile time. With a visible trip count of 2, LLVM flattened both iterations
// (despite `#pragma unroll 1`), live ranges exploded, and acc[32] spilled:
// R4 (128-VGPR cap) 5.1 GB scratch writes, R5 (256 VGPR) 1.9 GB. Round 1's
// identical body inside an 8-iteration rolled loop compiled to 80 VGPR, zero
// spill. `ng` is a runtime kernel arg (always 2) purely to force the rolled
// loop shape.
__global__ __launch_bounds__(256) void dcn_kernel(
    const float* __restrict__ x,    // long_fea full tensor [nb,32,H,W]
    const float* __restrict__ om,   // per-batch [216][rows][W], batch stride 216*rows*W
    const float* __restrict__ w,    // [32,32,9]
    const float* __restrict__ bias,
    float* __restrict__ y,          // out full tensor [nb,32,H,W]
    int r0, int rows, int ng)
{
    int sub = threadIdx.x >> 6;     // 0..3
    int lpx = threadIdx.x & 63;
    int tiles_per_b = rows*WW/64;
    int nwg = gridDim.x;
    int bid = xcd_swizzle(blockIdx.x, nwg);
    int b = bid / tiles_per_b;
    int tile = bid % tiles_per_b;
    int pin = tile*64 + lpx;        // pixel within chunk
    int rr = pin >> 8;
    int cw = pin & 255;
    int h = r0 + rr;
    const float* xb = x + (size_t)b*CH*HWSZ;
    const float* omb = om + (size_t)b*216*rows*WW;
    size_t cstride = (size_t)rows*WW;
    size_t ppos = (size_t)rr*WW + cw;

    float acc[CH];
    #pragma unroll
    for (int o=0;o<CH;++o) acc[o] = 0.f;

    int g0 = sub*ng;
    #pragma unroll 1
    for (int g = g0; g < g0 + ng; ++g) {
        const float* xg = xb + (size_t)g*4*HWSZ;
        #pragma unroll
        for (int k=0;k<9;++k) {
            int oc = g*9+k;
            float dy = omb[(size_t)oc*cstride + ppos];
            float dx = omb[(size_t)(72+oc)*cstride + ppos];
            float mm = omb[(size_t)(144+oc)*cstride + ppos];
            mm = 1.f/(1.f + __expf(-mm));
            float py = dy + (float)(h + k/3 - 1);
            float px = dx + (float)(cw + k%3 - 1);
            float y0f = floorf(py), x0f = floorf(px);
            int yi = (int)y0f, xi = (int)x0f;
            float ty = py - y0f, tx = px - x0f;
            float w00 = (1.f-ty)*(1.f-tx), w01 = (1.f-ty)*tx;
            float w10 = ty*(1.f-tx),       w11 = ty*tx;
            int yc0 = min(max(yi,0),HH-1),   yc1 = min(max(yi+1,0),HH-1);
            int xc0 = min(max(xi,0),WW-1),   xc1 = min(max(xi+1,0),WW-1);
            bool vy0 = (yi>=0)&&(yi<HH),     vy1 = (yi+1>=0)&&(yi+1<HH);
            bool vx0 = (xi>=0)&&(xi<WW),     vx1 = (xi+1>=0)&&(xi+1<WW);
            float f00 = (vy0&&vx0)? w00*mm : 0.f;
            float f01 = (vy0&&vx1)? w01*mm : 0.f;
            float f10 = (vy1&&vx0)? w10*mm : 0.f;
            float f11 = (vy1&&vx1)? w11*mm : 0.f;
            int i00 = yc0*WW+xc0, i01 = yc0*WW+xc1;
            int i10 = yc1*WW+xc0, i11 = yc1*WW+xc1;
            #pragma unroll
            for (int c=0;c<4;++c) {
                const float* xc = xg + (size_t)c*HWSZ;
                float val = xc[i00]*f00 + xc[i01]*f01 + xc[i10]*f10 + xc[i11]*f11;
                const float* wp = w + (size_t)(g*4+c)*9 + k;   // + o*288
                #pragma unroll
                for (int o=0;o<CH;++o)
                    acc[o] += wp[(size_t)o*288] * val;
            }
        }
    }

    // Tree reduce: sub2->sub0, sub3->sub1; then sub1->sub0.
    __shared__ float L[128][33];
    if (sub >= 2) {
        #pragma unroll
        for (int o=0;o<CH;++o) L[(sub-2)*64 + lpx][o] = acc[o];
    }
    __syncthreads();
    if (sub < 2) {
        #pragma unroll
        for (int o=0;o<CH;++o) acc[o] += L[sub*64 + lpx][o];
    }
    __syncthreads();
    if (sub == 1) {
        #pragma unroll
        for (int o=0;o<CH;++o) L[lpx][o] = acc[o];
    }
    __syncthreads();
    if (sub == 0) {
        float* yp = y + (size_t)b*CH*HWSZ + (size_t)h*WW + cw;
        #pragma unroll
        for (int o=0;o<CH;++o)
            yp[(size_t)o*HWSZ] = lrelu_f(acc[o] + L[lpx][o] + bias[o]);
    }
}

extern "C" void kernel_launch(void* const* d_in, const int* in_sizes, int n_in,
                              void* d_out, int out_size, void* d_ws, size_t ws_size,
                              hipStream_t stream)
{
    (void)in_sizes; (void)n_in; (void)out_size;
    const float* short_fea = (const float*)d_in[0];
    const float* long_fea  = (const float*)d_in[1];
    const float* prev      = (const float*)d_in[2];
    const float* conv1_w   = (const float*)d_in[3];
    const float* conv1_b   = (const float*)d_in[4];
    const float* oc1_w     = (const float*)d_in[5];
    const float* oc1_b     = (const float*)d_in[6];
    const float* oc2_w     = (const float*)d_in[7];
    const float* oc2_b     = (const float*)d_in[8];
    const float* oc3_w     = (const float*)d_in[9];
    const float* oc3_b     = (const float*)d_in[10];
    const float* dow       = (const float*)d_in[11];
    const float* dob       = (const float*)d_in[12];
    const float* dcw       = (const float*)d_in[13];
    const float* dcb       = (const float*)d_in[14];

    float* out = (float*)d_out;                       // [2,32,256,256]
    float* off_out = out + (size_t)2*CH*HWSZ;         // [2,32,256,256]

    float* bufB = (float*)d_ws;                       // 16 MB
    float* bufU = bufB + (size_t)2*CH*HWSZ;           // 16 MB
    float* om   = bufU + (size_t)2*CH*HWSZ;
    size_t used = (size_t)2 * 2*CH*HWSZ * sizeof(float);
    size_t avail = (ws_size > used) ? (ws_size - used) : 0;
    size_t full_om_bytes = (size_t)216 * HWSZ * sizeof(float);   // per batch

    const int PIX_BLOCKS = (2*HWSZ)/256;   // 512

    // conv1 (1x1, no act): (short,long) -> out region (temp)
    conv1x1_kernel<<<PIX_BLOCKS, 256, 0, stream>>>(short_fea, long_fea, conv1_w, conv1_b, out);
    // oc1 (3x3, lrelu): out -> bufB
    conv3x3_kernel<1><<<PIX_BLOCKS, 256, 0, stream>>>(out, nullptr, oc1_w, oc1_b, bufB, 1);
    // up2: prev -> bufU  (includes the *2.0)
    up2_kernel<<<(2*CH*HWSZ)/256, 256, 0, stream>>>(prev, bufU);
    // oc2 (3x3 on concat(bufB,bufU), lrelu): -> out region (temp)
    conv3x3_kernel<2><<<PIX_BLOCKS, 256, 0, stream>>>(bufB, bufU, oc2_w, oc2_b, out, 1);
    // oc3 (3x3, lrelu): out -> off_out  (this is output #2)
    conv3x3_kernel<1><<<PIX_BLOCKS, 256, 0, stream>>>(out, nullptr, oc3_w, oc3_b, off_out, 1);

    if (avail >= 2*full_om_bytes) {
        // Both batches in single launches: max occupancy.
        dim3 g1(2*HH, 9);
        dcn_off_kernel<<<g1, 256, 0, stream>>>(off_out, dow, dob, om, 0, HH);
        int tiles = 2*HWSZ/64;   // 2048 blocks
        dcn_kernel<<<tiles, 256, 0, stream>>>(long_fea, om, dcw, dcb, out, 0, HH, 2);
    } else {
        // Chunked per batch fallback.
        size_t per_row = (size_t)216 * WW * sizeof(float);
        int rows_chunk = (int)(avail / per_row);
        if (rows_chunk < 1) rows_chunk = 1;
        if (rows_chunk > HH) rows_chunk = HH;
        for (int b=0;b<2;++b) {
            const float* offb = off_out + (size_t)b*CH*HWSZ;
            const float* lfb  = long_fea + (size_t)b*CH*HWSZ;
            float* outb = out + (size_t)b*CH*HWSZ;
            for (int r0=0;r0<HH;r0+=rows_chunk) {
                int rows = (HH - r0 < rows_chunk) ? (HH - r0) : rows_chunk;
                dim3 g1(rows, 9);
                dcn_off_kernel<<<g1, 256, 0, stream>>>(offb, dow, dob, om, r0, rows);
                dcn_kernel<<<rows*WW/64, 256, 0, stream>>>(lfb, om, dcw, dcb, outb, r0, rows, 2);
            }
        }
    }
}

// Round 8
// 1079.321 us; speedup vs baseline: 2.0093x; 2.0093x over previous
//
#include <hip/hip_runtime.h>

#define HH 256
#define WW 256
#define HWSZ (HH*WW)
#define CH 32

__device__ __forceinline__ float lrelu_f(float x){ return x >= 0.f ? x : 0.2f*x; }

// 1x1 conv over concat(short, long): y[b,o,hw] = bias[o] + sum_c w[o][c]*s + w[o][32+c]*l
__global__ __launch_bounds__(256) void conv1x1_kernel(
    const float* __restrict__ s, const float* __restrict__ l,
    const float* __restrict__ w, const float* __restrict__ bias,
    float* __restrict__ y)
{
    int gid = blockIdx.x*256 + threadIdx.x;   // over 2*HWSZ
    int b = gid >> 16;
    int pix = gid & (HWSZ-1);
    const float* sp = s + (size_t)b*CH*HWSZ + pix;
    const float* lp = l + (size_t)b*CH*HWSZ + pix;
    float acc[CH];
    #pragma unroll
    for (int o=0;o<CH;++o) acc[o] = bias[o];
    for (int c=0;c<CH;++c) {
        float v = sp[(size_t)c*HWSZ];
        #pragma unroll
        for (int o=0;o<CH;++o) acc[o] += w[o*64+c]*v;
    }
    for (int c=0;c<CH;++c) {
        float v = lp[(size_t)c*HWSZ];
        #pragma unroll
        for (int o=0;o<CH;++o) acc[o] += w[o*64+32+c]*v;
    }
    float* yp = y + (size_t)b*CH*HWSZ + pix;
    #pragma unroll
    for (int o=0;o<CH;++o) yp[(size_t)o*HWSZ] = acc[o];
}

// 3x3 conv, pad=1, Cout=32, Cin = 32*NP (phase 0 from x0, phase 1 from x1). Optional lrelu.
template<int NP>
__global__ __launch_bounds__(256) void conv3x3_kernel(
    const float* __restrict__ x0, const float* __restrict__ x1,
    const float* __restrict__ w, const float* __restrict__ bias,
    float* __restrict__ y, int relu)
{
    int gid = blockIdx.x*256 + threadIdx.x;   // over 2*HWSZ
    int b = gid >> 16;
    int pix = gid & (HWSZ-1);
    int h = pix >> 8, cw = pix & 255;
    const int CIN = 32*NP;
    float acc[CH];
    #pragma unroll
    for (int o=0;o<CH;++o) acc[o] = bias[o];
    #pragma unroll
    for (int p=0;p<NP;++p) {
        const float* src = (p==0) ? x0 : x1;
        const float* xb = src + (size_t)b*CH*HWSZ;
        for (int c=0;c<CH;++c) {
            const float* xp = xb + (size_t)c*HWSZ;
            float v[9];
            #pragma unroll
            for (int t=0;t<9;++t) {
                int hh = h + t/3 - 1;
                int wx = cw + t%3 - 1;
                v[t] = (hh>=0 && hh<HH && wx>=0 && wx<WW) ? xp[hh*WW+wx] : 0.f;
            }
            const float* wp = w + (size_t)(p*32 + c)*9;   // + o*CIN*9 + t
            #pragma unroll
            for (int o=0;o<CH;++o) {
                #pragma unroll
                for (int t=0;t<9;++t)
                    acc[o] += wp[(size_t)o*CIN*9 + t] * v[t];
            }
        }
    }
    float* yp = y + (size_t)b*CH*HWSZ + pix;
    #pragma unroll
    for (int o=0;o<CH;++o)
        yp[(size_t)o*HWSZ] = relu ? lrelu_f(acc[o]) : acc[o];
}

// bilinear x2 upsample (align_corners=False) of [2,32,128,128] -> [2,32,256,256], times 2.0
__global__ __launch_bounds__(256) void up2_kernel(
    const float* __restrict__ x, float* __restrict__ y)
{
    int gid = blockIdx.x*256 + threadIdx.x;   // over 2*32*256*256
    int ow = gid & 255;
    int oh = (gid >> 8) & 255;
    int bc = gid >> 16;                        // 0..63
    const int Hin = 128, Win = 128;
    float cy = (oh + 0.5f)*0.5f - 0.5f;
    float cx = (ow + 0.5f)*0.5f - 0.5f;
    cy = fminf(fmaxf(cy, 0.f), (float)(Hin-1));
    cx = fminf(fmaxf(cx, 0.f), (float)(Win-1));
    int y0 = (int)floorf(cy);
    int x0 = (int)floorf(cx);
    int y1 = min(y0+1, Hin-1);
    int x1 = min(x0+1, Win-1);
    float ty = cy - (float)y0, tx = cx - (float)x0;
    const float* xp = x + (size_t)bc*Hin*Win;
    float v00 = xp[y0*Win+x0], v01 = xp[y0*Win+x1];
    float v10 = xp[y1*Win+x0], v11 = xp[y1*Win+x1];
    float v = v00*(1.f-ty)*(1.f-tx) + v01*(1.f-ty)*tx + v10*ty*(1.f-tx) + v11*ty*tx;
    y[gid] = 2.0f*v;
}

// 3x3 conv 32 -> 216 (no act). Covers nb batches, rows [r0, r0+rows) of each.
// grid.x = nb*rows (b-major), grid.y = 9 (24 out-chans each).
// om layout per batch: [216][rows][W], batch stride 216*rows*W.
__global__ __launch_bounds__(256) void dcn_off_kernel(
    const float* __restrict__ x,    // off full tensor [nb,32,H,W]
    const float* __restrict__ w,    // [216,32,9]
    const float* __restrict__ bias,
    float* __restrict__ om,
    int r0, int rows)
{
    int b = blockIdx.x / rows;
    int rr = blockIdx.x % rows;
    int cw = threadIdx.x;
    int h = r0 + rr;
    int oc0 = blockIdx.y*24;
    const float* xb = x + (size_t)b*CH*HWSZ;
    float* omb = om + (size_t)b*216*rows*WW;
    float acc[24];
    #pragma unroll
    for (int j=0;j<24;++j) acc[j] = bias[oc0+j];
    for (int c=0;c<32;++c) {
        const float* xp = xb + (size_t)c*HWSZ;
        float v[9];
        #pragma unroll
        for (int t=0;t<9;++t) {
            int hh = h + t/3 - 1;
            int wx = cw + t%3 - 1;
            v[t] = (hh>=0 && hh<HH && wx>=0 && wx<WW) ? xp[hh*WW+wx] : 0.f;
        }
        const float* wp = w + (size_t)c*9;   // + (oc0+j)*288 + t
        #pragma unroll
        for (int j=0;j<24;++j) {
            #pragma unroll
            for (int t=0;t<9;++t)
                acc[j] += wp[(size_t)(oc0+j)*288 + t] * v[t];
        }
    }
    #pragma unroll
    for (int j=0;j<24;++j)
        omb[(size_t)(oc0+j)*rows*WW + (size_t)rr*WW + cw] = acc[j];
}

// DCNv2 sampling + einsum + bias + lrelu.
// R6 post-mortem: group-split + LDS-reduce variants all spilled (256 VGPR,
// GBs of scratch) regardless of loop rolling. This kernel returns EXACTLY to
// round-1's proven codegen shape (runtime g-loop over all 8 groups, k-unroll,
// direct store, no LDS, 80 VGPR, zero spill) and gets parallelism from a
// DISJOINT output-channel split instead: blockIdx.y = os picks 8 of 32 output
// channels; sampling math is recomputed per slice (cheap, ~35 us chip-wide)
// and acc shrinks 32->8. grid (nb*rows, 4) -> 8192 waves = 8/SIMD.
__global__ __launch_bounds__(256) void dcn_kernel(
    const float* __restrict__ x,    // long_fea base [nb,32,H,W]
    const float* __restrict__ om,   // per-batch [216][rows][W], batch stride 216*rows*W
    const float* __restrict__ w,    // [32,32,9]
    const float* __restrict__ bias,
    float* __restrict__ y,          // out base [nb,32,H,W]
    int r0, int rows)
{
    int os = blockIdx.y;                     // 0..3: output channels [8*os, 8*os+8)
    int pix_gid = blockIdx.x*256 + threadIdx.x;   // over nb*rows*WW
    int rowsWW = rows*WW;
    int b = pix_gid / rowsWW;                // one-time runtime div
    int pin = pix_gid - b*rowsWW;
    int rr = pin >> 8;
    int cw = pin & 255;
    int h = r0 + rr;
    const float* xb = x + (size_t)b*CH*HWSZ;
    const float* omb = om + (size_t)b*216*rowsWW;
    size_t cstride = (size_t)rowsWW;
    size_t ppos = (size_t)rr*WW + cw;
    int ob = os*8;

    float acc[8];
    #pragma unroll
    for (int o=0;o<8;++o) acc[o] = bias[ob+o];

    for (int g=0; g<8; ++g) {
        const float* xg = xb + (size_t)g*4*HWSZ;
        #pragma unroll
        for (int k=0;k<9;++k) {
            int oc = g*9+k;
            float dy = omb[(size_t)oc*cstride + ppos];
            float dx = omb[(size_t)(72+oc)*cstride + ppos];
            float mm = omb[(size_t)(144+oc)*cstride + ppos];
            mm = 1.f/(1.f + __expf(-mm));
            float py = dy + (float)(h + k/3 - 1);
            float px = dx + (float)(cw + k%3 - 1);
            float y0f = floorf(py), x0f = floorf(px);
            int yi = (int)y0f, xi = (int)x0f;
            float ty = py - y0f, tx = px - x0f;
            float w00 = (1.f-ty)*(1.f-tx), w01 = (1.f-ty)*tx;
            float w10 = ty*(1.f-tx),       w11 = ty*tx;
            int yc0 = min(max(yi,0),HH-1),   yc1 = min(max(yi+1,0),HH-1);
            int xc0 = min(max(xi,0),WW-1),   xc1 = min(max(xi+1,0),WW-1);
            bool vy0 = (yi>=0)&&(yi<HH),     vy1 = (yi+1>=0)&&(yi+1<HH);
            bool vx0 = (xi>=0)&&(xi<WW),     vx1 = (xi+1>=0)&&(xi+1<WW);
            float f00 = (vy0&&vx0)? w00*mm : 0.f;
            float f01 = (vy0&&vx1)? w01*mm : 0.f;
            float f10 = (vy1&&vx0)? w10*mm : 0.f;
            float f11 = (vy1&&vx1)? w11*mm : 0.f;
            int i00 = yc0*WW+xc0, i01 = yc0*WW+xc1;
            int i10 = yc1*WW+xc0, i11 = yc1*WW+xc1;
            #pragma unroll
            for (int c=0;c<4;++c) {
                const float* xc = xg + (size_t)c*HWSZ;
                float val = xc[i00]*f00 + xc[i01]*f01 + xc[i10]*f10 + xc[i11]*f11;
                const float* wp = w + (size_t)(g*4+c)*9 + k;   // + (ob+o)*288
                #pragma unroll
                for (int o=0;o<8;++o)
                    acc[o] += wp[(size_t)(ob+o)*288] * val;
            }
        }
    }

    float* yp = y + (size_t)b*CH*HWSZ + (size_t)h*WW + cw;
    #pragma unroll
    for (int o=0;o<8;++o)
        yp[(size_t)(ob+o)*HWSZ] = lrelu_f(acc[o]);
}

extern "C" void kernel_launch(void* const* d_in, const int* in_sizes, int n_in,
                              void* d_out, int out_size, void* d_ws, size_t ws_size,
                              hipStream_t stream)
{
    (void)in_sizes; (void)n_in; (void)out_size;
    const float* short_fea = (const float*)d_in[0];
    const float* long_fea  = (const float*)d_in[1];
    const float* prev      = (const float*)d_in[2];
    const float* conv1_w   = (const float*)d_in[3];
    const float* conv1_b   = (const float*)d_in[4];
    const float* oc1_w     = (const float*)d_in[5];
    const float* oc1_b     = (const float*)d_in[6];
    const float* oc2_w     = (const float*)d_in[7];
    const float* oc2_b     = (const float*)d_in[8];
    const float* oc3_w     = (const float*)d_in[9];
    const float* oc3_b     = (const float*)d_in[10];
    const float* dow       = (const float*)d_in[11];
    const float* dob       = (const float*)d_in[12];
    const float* dcw       = (const float*)d_in[13];
    const float* dcb       = (const float*)d_in[14];

    float* out = (float*)d_out;                       // [2,32,256,256]
    float* off_out = out + (size_t)2*CH*HWSZ;         // [2,32,256,256]

    float* bufB = (float*)d_ws;                       // 16 MB
    float* bufU = bufB + (size_t)2*CH*HWSZ;           // 16 MB
    float* om   = bufU + (size_t)2*CH*HWSZ;
    size_t used = (size_t)2 * 2*CH*HWSZ * sizeof(float);
    size_t avail = (ws_size > used) ? (ws_size - used) : 0;
    size_t full_om_bytes = (size_t)216 * HWSZ * sizeof(float);   // per batch

    const int PIX_BLOCKS = (2*HWSZ)/256;   // 512

    // conv1 (1x1, no act): (short,long) -> out region (temp)
    conv1x1_kernel<<<PIX_BLOCKS, 256, 0, stream>>>(short_fea, long_fea, conv1_w, conv1_b, out);
    // oc1 (3x3, lrelu): out -> bufB
    conv3x3_kernel<1><<<PIX_BLOCKS, 256, 0, stream>>>(out, nullptr, oc1_w, oc1_b, bufB, 1);
    // up2: prev -> bufU  (includes the *2.0)
    up2_kernel<<<(2*CH*HWSZ)/256, 256, 0, stream>>>(prev, bufU);
    // oc2 (3x3 on concat(bufB,bufU), lrelu): -> out region (temp)
    conv3x3_kernel<2><<<PIX_BLOCKS, 256, 0, stream>>>(bufB, bufU, oc2_w, oc2_b, out, 1);
    // oc3 (3x3, lrelu): out -> off_out  (this is output #2)
    conv3x3_kernel<1><<<PIX_BLOCKS, 256, 0, stream>>>(out, nullptr, oc3_w, oc3_b, off_out, 1);

    if (avail >= 2*full_om_bytes) {
        // Both batches in single launches.
        dim3 g1(2*HH, 9);
        dcn_off_kernel<<<g1, 256, 0, stream>>>(off_out, dow, dob, om, 0, HH);
        dim3 g2(2*HWSZ/256, 4);   // (512, 4) = 2048 blocks, 8 waves/SIMD
        dcn_kernel<<<g2, 256, 0, stream>>>(long_fea, om, dcw, dcb, out, 0, HH);
    } else {
        // Chunked per batch fallback.
        size_t per_row = (size_t)216 * WW * sizeof(float);
        int rows_chunk = (int)(avail / per_row);
        if (rows_chunk < 1) rows_chunk = 1;
        if (rows_chunk > HH) rows_chunk = HH;
        for (int b=0;b<2;++b) {
            const float* offb = off_out + (size_t)b*CH*HWSZ;
            const float* lfb  = long_fea + (size_t)b*CH*HWSZ;
            float* outb = out + (size_t)b*CH*HWSZ;
            for (int r0=0;r0<HH;r0+=rows_chunk) {
                int rows = (HH - r0 < rows_chunk) ? (HH - r0) : rows_chunk;
                dim3 g1(rows, 9);
                dcn_off_kernel<<<g1, 256, 0, stream>>>(offb, dow, dob, om, r0, rows);
                dim3 g2(rows*WW/256, 4);
                dcn_kernel<<<g2, 256, 0, stream>>>(lfb, om, dcw, dcb, outb, r0, rows);
            }
        }
    }
}

// Round 9
// 815.364 us; speedup vs baseline: 2.6597x; 1.3237x over previous
//
#include <hip/hip_runtime.h>

#define HH 256
#define WW 256
#define HWSZ (HH*WW)
#define CH 32

__device__ __forceinline__ float lrelu_f(float x){ return x >= 0.f ? x : 0.2f*x; }

// 1x1 conv over concat(short, long): y[b,o,hw] = bias[o] + sum_c w[o][c]*s + w[o][32+c]*l
__global__ __launch_bounds__(256) void conv1x1_kernel(
    const float* __restrict__ s, const float* __restrict__ l,
    const float* __restrict__ w, const float* __restrict__ bias,
    float* __restrict__ y)
{
    int gid = blockIdx.x*256 + threadIdx.x;   // over 2*HWSZ
    int b = gid >> 16;
    int pix = gid & (HWSZ-1);
    const float* sp = s + (size_t)b*CH*HWSZ + pix;
    const float* lp = l + (size_t)b*CH*HWSZ + pix;
    float acc[CH];
    #pragma unroll
    for (int o=0;o<CH;++o) acc[o] = bias[o];
    for (int c=0;c<CH;++c) {
        float v = sp[(size_t)c*HWSZ];
        #pragma unroll
        for (int o=0;o<CH;++o) acc[o] += w[o*64+c]*v;
    }
    for (int c=0;c<CH;++c) {
        float v = lp[(size_t)c*HWSZ];
        #pragma unroll
        for (int o=0;o<CH;++o) acc[o] += w[o*64+32+c]*v;
    }
    float* yp = y + (size_t)b*CH*HWSZ + pix;
    #pragma unroll
    for (int o=0;o<CH;++o) yp[(size_t)o*HWSZ] = acc[o];
}

// 3x3 conv, pad=1, Cout=32, Cin = 32*NP (phase 0 from x0, phase 1 from x1). Optional lrelu.
template<int NP>
__global__ __launch_bounds__(256) void conv3x3_kernel(
    const float* __restrict__ x0, const float* __restrict__ x1,
    const float* __restrict__ w, const float* __restrict__ bias,
    float* __restrict__ y, int relu)
{
    int gid = blockIdx.x*256 + threadIdx.x;   // over 2*HWSZ
    int b = gid >> 16;
    int pix = gid & (HWSZ-1);
    int h = pix >> 8, cw = pix & 255;
    const int CIN = 32*NP;
    float acc[CH];
    #pragma unroll
    for (int o=0;o<CH;++o) acc[o] = bias[o];
    #pragma unroll
    for (int p=0;p<NP;++p) {
        const float* src = (p==0) ? x0 : x1;
        const float* xb = src + (size_t)b*CH*HWSZ;
        for (int c=0;c<CH;++c) {
            const float* xp = xb + (size_t)c*HWSZ;
            float v[9];
            #pragma unroll
            for (int t=0;t<9;++t) {
                int hh = h + t/3 - 1;
                int wx = cw + t%3 - 1;
                v[t] = (hh>=0 && hh<HH && wx>=0 && wx<WW) ? xp[hh*WW+wx] : 0.f;
            }
            const float* wp = w + (size_t)(p*32 + c)*9;   // + o*CIN*9 + t
            #pragma unroll
            for (int o=0;o<CH;++o) {
                #pragma unroll
                for (int t=0;t<9;++t)
                    acc[o] += wp[(size_t)o*CIN*9 + t] * v[t];
            }
        }
    }
    float* yp = y + (size_t)b*CH*HWSZ + pix;
    #pragma unroll
    for (int o=0;o<CH;++o)
        yp[(size_t)o*HWSZ] = relu ? lrelu_f(acc[o]) : acc[o];
}

// bilinear x2 upsample (align_corners=False) of [2,32,128,128] -> [2,32,256,256], times 2.0
__global__ __launch_bounds__(256) void up2_kernel(
    const float* __restrict__ x, float* __restrict__ y)
{
    int gid = blockIdx.x*256 + threadIdx.x;   // over 2*32*256*256
    int ow = gid & 255;
    int oh = (gid >> 8) & 255;
    int bc = gid >> 16;                        // 0..63
    const int Hin = 128, Win = 128;
    float cy = (oh + 0.5f)*0.5f - 0.5f;
    float cx = (ow + 0.5f)*0.5f - 0.5f;
    cy = fminf(fmaxf(cy, 0.f), (float)(Hin-1));
    cx = fminf(fmaxf(cx, 0.f), (float)(Win-1));
    int y0 = (int)floorf(cy);
    int x0 = (int)floorf(cx);
    int y1 = min(y0+1, Hin-1);
    int x1 = min(x0+1, Win-1);
    float ty = cy - (float)y0, tx = cx - (float)x0;
    const float* xp = x + (size_t)bc*Hin*Win;
    float v00 = xp[y0*Win+x0], v01 = xp[y0*Win+x1];
    float v10 = xp[y1*Win+x0], v11 = xp[y1*Win+x1];
    float v = v00*(1.f-ty)*(1.f-tx) + v01*(1.f-ty)*tx + v10*ty*(1.f-tx) + v11*ty*tx;
    y[gid] = 2.0f*v;
}

// 3x3 conv 32 -> 216 (no act). Covers nb batches, rows [r0, r0+rows) of each.
// grid.x = nb*rows (b-major), grid.y = 9 (24 out-chans each).
// om layout per batch: [216][rows][W], batch stride 216*rows*W.
__global__ __launch_bounds__(256) void dcn_off_kernel(
    const float* __restrict__ x,    // off full tensor [nb,32,H,W]
    const float* __restrict__ w,    // [216,32,9]
    const float* __restrict__ bias,
    float* __restrict__ om,
    int r0, int rows)
{
    int b = blockIdx.x / rows;
    int rr = blockIdx.x % rows;
    int cw = threadIdx.x;
    int h = r0 + rr;
    int oc0 = blockIdx.y*24;
    const float* xb = x + (size_t)b*CH*HWSZ;
    float* omb = om + (size_t)b*216*rows*WW;
    float acc[24];
    #pragma unroll
    for (int j=0;j<24;++j) acc[j] = bias[oc0+j];
    for (int c=0;c<32;++c) {
        const float* xp = xb + (size_t)c*HWSZ;
        float v[9];
        #pragma unroll
        for (int t=0;t<9;++t) {
            int hh = h + t/3 - 1;
            int wx = cw + t%3 - 1;
            v[t] = (hh>=0 && hh<HH && wx>=0 && wx<WW) ? xp[hh*WW+wx] : 0.f;
        }
        const float* wp = w + (size_t)c*9;   // + (oc0+j)*288 + t
        #pragma unroll
        for (int j=0;j<24;++j) {
            #pragma unroll
            for (int t=0;t<9;++t)
                acc[j] += wp[(size_t)(oc0+j)*288 + t] * v[t];
        }
    }
    #pragma unroll
    for (int j=0;j<24;++j)
        omb[(size_t)(oc0+j)*rows*WW + (size_t)rr*WW + cw] = acc[j];
}

// DCNv2 sampling + einsum + bias + lrelu.
// R8 post-mortem: VALUBusy was dominated by ADDRESS MATH (per-lane 64-bit
// muls for om strides, 64-bit gather address carries), duplicated 4x by the
// os-split. This version: (1) os-split reduced to 2 slices of 16 channels
// (acc[16], still far from the 44+spill cliff); (2) batch/slice moved to
// blockIdx.z/y so every base pointer and stride product is WAVE-UNIFORM ->
// SALU/scalar loads; per-lane part is a single 32-bit ppos / i00 voffset.
// grid (rows, 2, nb): one row of 256 px per block.
__global__ __launch_bounds__(256) void dcn_kernel(
    const float* __restrict__ x,    // long_fea base [nb,32,H,W]
    const float* __restrict__ om,   // per-batch [216][rows][W], batch stride 216*rows*W
    const float* __restrict__ w,    // [32,32,9]
    const float* __restrict__ bias,
    float* __restrict__ y,          // out base [nb,32,H,W]
    int r0, int rows)
{
    const int b  = blockIdx.z;               // SGPR
    const int os = blockIdx.y;               // SGPR: output channels [16*os, 16*os+16)
    const int rowsWW = rows*WW;
    int rr = blockIdx.x;                     // row within chunk (SGPR)
    int cw = threadIdx.x;                    // 0..255
    int h = r0 + rr;
    const float* xb  = x  + (size_t)b*CH*HWSZ;        // scalar
    const float* omb = om + (size_t)b*216*rowsWW;     // scalar
    int ppos = rr*WW + cw;                   // per-lane 32-bit offset
    int ob = os*16;

    float acc[16];
    #pragma unroll
    for (int o=0;o<16;++o) acc[o] = bias[ob+o];

    for (int g=0; g<8; ++g) {
        const float* xg = xb + (size_t)g*4*HWSZ;      // scalar
        #pragma unroll
        for (int k=0;k<9;++k) {
            int oc = g*9+k;                           // uniform
            const float* p_dy = omb + (size_t)oc*rowsWW;          // scalar math
            const float* p_dx = omb + (size_t)(72+oc)*rowsWW;
            const float* p_mm = omb + (size_t)(144+oc)*rowsWW;
            float dy = p_dy[ppos];
            float dx = p_dx[ppos];
            float mm = p_mm[ppos];
            mm = 1.f/(1.f + __expf(-mm));
            float py = dy + (float)(h + k/3 - 1);
            float px = dx + (float)(cw + k%3 - 1);
            float y0f = floorf(py), x0f = floorf(px);
            int yi = (int)y0f, xi = (int)x0f;
            float ty = py - y0f, tx = px - x0f;
            float w00 = (1.f-ty)*(1.f-tx), w01 = (1.f-ty)*tx;
            float w10 = ty*(1.f-tx),       w11 = ty*tx;
            int yc0 = min(max(yi,0),HH-1),   yc1 = min(max(yi+1,0),HH-1);
            int xc0 = min(max(xi,0),WW-1),   xc1 = min(max(xi+1,0),WW-1);
            bool vy0 = (yi>=0)&&(yi<HH),     vy1 = (yi+1>=0)&&(yi+1<HH);
            bool vx0 = (xi>=0)&&(xi<WW),     vx1 = (xi+1>=0)&&(xi+1<WW);
            float f00 = (vy0&&vx0)? w00*mm : 0.f;
            float f01 = (vy0&&vx1)? w01*mm : 0.f;
            float f10 = (vy1&&vx0)? w10*mm : 0.f;
            float f11 = (vy1&&vx1)? w11*mm : 0.f;
            int i00 = yc0*WW+xc0, i01 = yc0*WW+xc1;   // per-lane 32-bit voffsets
            int i10 = yc1*WW+xc0, i11 = yc1*WW+xc1;
            #pragma unroll
            for (int c=0;c<4;++c) {
                const float* xc = xg + (size_t)c*HWSZ;            // scalar
                float val = xc[i00]*f00 + xc[i01]*f01 + xc[i10]*f10 + xc[i11]*f11;
                const float* wp = w + (size_t)(g*4+c)*9 + k;      // scalar
                #pragma unroll
                for (int o=0;o<16;++o)
                    acc[o] += wp[(size_t)(ob+o)*288] * val;       // scalar weight loads
            }
        }
    }

    float* yb = y + (size_t)(b*CH + ob)*HWSZ + (size_t)h*WW;      // scalar + row
    #pragma unroll
    for (int o=0;o<16;++o)
        yb[(size_t)o*HWSZ + cw] = lrelu_f(acc[o]);
}

extern "C" void kernel_launch(void* const* d_in, const int* in_sizes, int n_in,
                              void* d_out, int out_size, void* d_ws, size_t ws_size,
                              hipStream_t stream)
{
    (void)in_sizes; (void)n_in; (void)out_size;
    const float* short_fea = (const float*)d_in[0];
    const float* long_fea  = (const float*)d_in[1];
    const float* prev      = (const float*)d_in[2];
    const float* conv1_w   = (const float*)d_in[3];
    const float* conv1_b   = (const float*)d_in[4];
    const float* oc1_w     = (const float*)d_in[5];
    const float* oc1_b     = (const float*)d_in[6];
    const float* oc2_w     = (const float*)d_in[7];
    const float* oc2_b     = (const float*)d_in[8];
    const float* oc3_w     = (const float*)d_in[9];
    const float* oc3_b     = (const float*)d_in[10];
    const float* dow       = (const float*)d_in[11];
    const float* dob       = (const float*)d_in[12];
    const float* dcw       = (const float*)d_in[13];
    const float* dcb       = (const float*)d_in[14];

    float* out = (float*)d_out;                       // [2,32,256,256]
    float* off_out = out + (size_t)2*CH*HWSZ;         // [2,32,256,256]

    float* bufB = (float*)d_ws;                       // 16 MB
    float* bufU = bufB + (size_t)2*CH*HWSZ;           // 16 MB
    float* om   = bufU + (size_t)2*CH*HWSZ;
    size_t used = (size_t)2 * 2*CH*HWSZ * sizeof(float);
    size_t avail = (ws_size > used) ? (ws_size - used) : 0;
    size_t full_om_bytes = (size_t)216 * HWSZ * sizeof(float);   // per batch

    const int PIX_BLOCKS = (2*HWSZ)/256;   // 512

    // conv1 (1x1, no act): (short,long) -> out region (temp)
    conv1x1_kernel<<<PIX_BLOCKS, 256, 0, stream>>>(short_fea, long_fea, conv1_w, conv1_b, out);
    // oc1 (3x3, lrelu): out -> bufB
    conv3x3_kernel<1><<<PIX_BLOCKS, 256, 0, stream>>>(out, nullptr, oc1_w, oc1_b, bufB, 1);
    // up2: prev -> bufU  (includes the *2.0)
    up2_kernel<<<(2*CH*HWSZ)/256, 256, 0, stream>>>(prev, bufU);
    // oc2 (3x3 on concat(bufB,bufU), lrelu): -> out region (temp)
    conv3x3_kernel<2><<<PIX_BLOCKS, 256, 0, stream>>>(bufB, bufU, oc2_w, oc2_b, out, 1);
    // oc3 (3x3, lrelu): out -> off_out  (this is output #2)
    conv3x3_kernel<1><<<PIX_BLOCKS, 256, 0, stream>>>(out, nullptr, oc3_w, oc3_b, off_out, 1);

    if (avail >= 2*full_om_bytes) {
        // Both batches in single launches.
        dim3 g1(2*HH, 9);
        dcn_off_kernel<<<g1, 256, 0, stream>>>(off_out, dow, dob, om, 0, HH);
        dim3 g2(HH, 2, 2);   // (row, os-slice, batch) = 1024 blocks, 4 waves/SIMD
        dcn_kernel<<<g2, 256, 0, stream>>>(long_fea, om, dcw, dcb, out, 0, HH);
    } else {
        // Chunked per batch fallback.
        size_t per_row = (size_t)216 * WW * sizeof(float);
        int rows_chunk = (int)(avail / per_row);
        if (rows_chunk < 1) rows_chunk = 1;
        if (rows_chunk > HH) rows_chunk = HH;
        for (int b=0;b<2;++b) {
            const float* offb = off_out + (size_t)b*CH*HWSZ;
            const float* lfb  = long_fea + (size_t)b*CH*HWSZ;
            float* outb = out + (size_t)b*CH*HWSZ;
            for (int r0=0;r0<HH;r0+=rows_chunk) {
                int rows = (HH - r0 < rows_chunk) ? (HH - r0) : rows_chunk;
                dim3 g1(rows, 9);
                dcn_off_kernel<<<g1, 256, 0, stream>>>(offb, dow, dob, om, r0, rows);
                dim3 g2(rows, 2, 1);
                dcn_kernel<<<g2, 256, 0, stream>>>(lfb, om, dcw, dcb, outb, r0, rows);
            }
        }
    }
}

// Round 10
// 631.425 us; speedup vs baseline: 3.4345x; 1.2913x over previous
//
#include <hip/hip_runtime.h>

#define HH 256
#define WW 256
#define HWSZ (HH*WW)
#define CH 32

typedef __attribute__((ext_vector_type(8))) short bfrag;   // 8 bf16 = 4 VGPRs
typedef __attribute__((ext_vector_type(4))) float f32x4;

__device__ __forceinline__ float lrelu_f(float x){ return x >= 0.f ? x : 0.2f*x; }

__device__ __forceinline__ unsigned short bf16_rne(float f){
    unsigned int u = __float_as_uint(f);
    unsigned int r = (u + 0x7fffu + ((u >> 16) & 1u)) >> 16;
    return (unsigned short)r;
}

// 1x1 conv over concat(short, long)
__global__ __launch_bounds__(256) void conv1x1_kernel(
    const float* __restrict__ s, const float* __restrict__ l,
    const float* __restrict__ w, const float* __restrict__ bias,
    float* __restrict__ y)
{
    int gid = blockIdx.x*256 + threadIdx.x;
    int b = gid >> 16;
    int pix = gid & (HWSZ-1);
    const float* sp = s + (size_t)b*CH*HWSZ + pix;
    const float* lp = l + (size_t)b*CH*HWSZ + pix;
    float acc[CH];
    #pragma unroll
    for (int o=0;o<CH;++o) acc[o] = bias[o];
    for (int c=0;c<CH;++c) {
        float v = sp[(size_t)c*HWSZ];
        #pragma unroll
        for (int o=0;o<CH;++o) acc[o] += w[o*64+c]*v;
    }
    for (int c=0;c<CH;++c) {
        float v = lp[(size_t)c*HWSZ];
        #pragma unroll
        for (int o=0;o<CH;++o) acc[o] += w[o*64+32+c]*v;
    }
    float* yp = y + (size_t)b*CH*HWSZ + pix;
    #pragma unroll
    for (int o=0;o<CH;++o) yp[(size_t)o*HWSZ] = acc[o];
}

// 3x3 conv, pad=1, Cout=32, Cin=32*NP
template<int NP>
__global__ __launch_bounds__(256) void conv3x3_kernel(
    const float* __restrict__ x0, const float* __restrict__ x1,
    const float* __restrict__ w, const float* __restrict__ bias,
    float* __restrict__ y, int relu)
{
    int gid = blockIdx.x*256 + threadIdx.x;
    int b = gid >> 16;
    int pix = gid & (HWSZ-1);
    int h = pix >> 8, cw = pix & 255;
    const int CIN = 32*NP;
    float acc[CH];
    #pragma unroll
    for (int o=0;o<CH;++o) acc[o] = bias[o];
    #pragma unroll
    for (int p=0;p<NP;++p) {
        const float* src = (p==0) ? x0 : x1;
        const float* xb = src + (size_t)b*CH*HWSZ;
        for (int c=0;c<CH;++c) {
            const float* xp = xb + (size_t)c*HWSZ;
            float v[9];
            #pragma unroll
            for (int t=0;t<9;++t) {
                int hh = h + t/3 - 1;
                int wx = cw + t%3 - 1;
                v[t] = (hh>=0 && hh<HH && wx>=0 && wx<WW) ? xp[hh*WW+wx] : 0.f;
            }
            const float* wp = w + (size_t)(p*32 + c)*9;
            #pragma unroll
            for (int o=0;o<CH;++o) {
                #pragma unroll
                for (int t=0;t<9;++t)
                    acc[o] += wp[(size_t)o*CIN*9 + t] * v[t];
            }
        }
    }
    float* yp = y + (size_t)b*CH*HWSZ + pix;
    #pragma unroll
    for (int o=0;o<CH;++o)
        yp[(size_t)o*HWSZ] = relu ? lrelu_f(acc[o]) : acc[o];
}

// bilinear x2 upsample + *2.0
__global__ __launch_bounds__(256) void up2_kernel(
    const float* __restrict__ x, float* __restrict__ y)
{
    int gid = blockIdx.x*256 + threadIdx.x;
    int ow = gid & 255;
    int oh = (gid >> 8) & 255;
    int bc = gid >> 16;
    const int Hin = 128, Win = 128;
    float cy = (oh + 0.5f)*0.5f - 0.5f;
    float cx = (ow + 0.5f)*0.5f - 0.5f;
    cy = fminf(fmaxf(cy, 0.f), (float)(Hin-1));
    cx = fminf(fmaxf(cx, 0.f), (float)(Win-1));
    int y0 = (int)floorf(cy);
    int x0 = (int)floorf(cx);
    int y1 = min(y0+1, Hin-1);
    int x1 = min(x0+1, Win-1);
    float ty = cy - (float)y0, tx = cx - (float)x0;
    const float* xp = x + (size_t)bc*Hin*Win;
    float v00 = xp[y0*Win+x0], v01 = xp[y0*Win+x1];
    float v10 = xp[y1*Win+x0], v11 = xp[y1*Win+x1];
    float v = v00*(1.f-ty)*(1.f-tx) + v01*(1.f-ty)*tx + v10*ty*(1.f-tx) + v11*ty*tx;
    y[gid] = 2.0f*v;
}

// ---- MFMA offset-conv path -------------------------------------------------

// NCHW fp32 -> NHWC bf16: xq[b][h][w][c]
__global__ __launch_bounds__(256) void nchw2nhwc_bf16(
    const float* __restrict__ x, unsigned short* __restrict__ xq)
{
    int gid = blockIdx.x*256 + threadIdx.x;   // nb*HWSZ
    int b = gid >> 16;
    int pix = gid & (HWSZ-1);
    const float* xp = x + (size_t)b*CH*HWSZ + pix;
    unsigned int pk[16];
    #pragma unroll
    for (int c2=0;c2<16;++c2) {
        unsigned int lo = bf16_rne(xp[(size_t)(2*c2)*HWSZ]);
        unsigned int hi = bf16_rne(xp[(size_t)(2*c2+1)*HWSZ]);
        pk[c2] = lo | (hi << 16);
    }
    unsigned int* op = reinterpret_cast<unsigned int*>(xq + (size_t)gid*32);
    #pragma unroll
    for (int i=0;i<16;++i) op[i] = pk[i];
}

// Pack dcn_off weights into A-fragment lane order:
// wp[ks][nt][lane][j] = dow[oc=nt*16+(l&15)][c=8*(l>>4)+j][t=ks], bf16 (0-pad oc>=216)
__global__ __launch_bounds__(256) void pack_w_bf16(
    const float* __restrict__ dow, unsigned short* __restrict__ wp)
{
    int gid = blockIdx.x*256 + threadIdx.x;   // 9*14*64 = 8064
    if (gid >= 9*14*64) return;
    int l = gid & 63;
    int rest = gid >> 6;
    int nt = rest % 14;
    int ks = rest / 14;
    int oc = nt*16 + (l & 15);
    int c0 = 8*(l >> 4);
    unsigned short outv[8];
    #pragma unroll
    for (int j=0;j<8;++j) {
        float v = (oc < 216) ? dow[(size_t)oc*288 + (size_t)(c0+j)*9 + ks] : 0.f;
        outv[j] = bf16_rne(v);
    }
    unsigned short* dst = wp + (size_t)gid*8;
    #pragma unroll
    for (int j=0;j<8;++j) dst[j] = outv[j];
}

// 3x3 conv 32->216 as 9 taps of MFMA 16x16x32 bf16 (fp32 accum).
// D[oc, pix]: A = packed weights, B = NHWC x. Per block: one h row, 64 w
// (4 waves x 16 px). grid.x = nb*HH*4.
// ks loop kept ROLLED (R4 lesson: full flatten -> register blowup).
__global__ __launch_bounds__(256) void dcn_off_mfma(
    const unsigned short* __restrict__ xq,   // [nb,H,W,32] bf16
    const unsigned short* __restrict__ wp,   // [9][14][64][8] bf16
    const float* __restrict__ bias,          // [216]
    float* __restrict__ om)                  // [nb][216][HWSZ]
{
    int bid = blockIdx.x;
    int wq = bid & 3;
    int h  = (bid >> 2) & 255;
    int b  = bid >> 10;
    int wv = threadIdx.x >> 6;
    int l  = threadIdx.x & 63;
    int w0 = wq*64 + wv*16;
    int lw = l & 15;
    int lq = l >> 4;

    f32x4 acc[14];
    #pragma unroll
    for (int t=0;t<14;++t) acc[t] = (f32x4){0.f,0.f,0.f,0.f};

    const unsigned short* xb = xq + (size_t)b*HWSZ*32;
    const bfrag zero = {0,0,0,0,0,0,0,0};

    #pragma unroll 1
    for (int ks=0; ks<9; ++ks) {
        int dy = ks/3 - 1, dx = ks%3 - 1;
        int hh = h + dy;
        if (hh < 0 || hh >= HH) continue;        // uniform skip (zero A row)
        int wx = w0 + lw + dx;
        bool vw = (wx >= 0) && (wx < WW);
        int wxc = min(max(wx, 0), WW-1);
        const unsigned short* xp = xb + ((size_t)hh*WW + wxc)*32 + lq*8;
        bfrag bfr = *reinterpret_cast<const bfrag*>(xp);
        bfr = vw ? bfr : zero;
        const unsigned short* wks = wp + (size_t)ks*14*64*8;
        #pragma unroll
        for (int nt=0; nt<14; ++nt) {
            bfrag afr = *reinterpret_cast<const bfrag*>(wks + ((size_t)nt*64 + l)*8);
            acc[nt] = __builtin_amdgcn_mfma_f32_16x16x32_bf16(afr, bfr, acc[nt], 0, 0, 0);
        }
    }

    // D[oc = nt*16 + lq*4 + i][pix = w0 + lw]; 16-lane groups -> coalesced stores
    float* omb = om + (size_t)b*216*HWSZ;
    size_t pbase = (size_t)h*WW + w0 + lw;
    #pragma unroll
    for (int nt=0; nt<14; ++nt) {
        #pragma unroll
        for (int i=0;i<4;++i) {
            int oc = nt*16 + lq*4 + i;
            if (oc < 216)
                omb[(size_t)oc*HWSZ + pbase] = acc[nt][i] + bias[oc];
        }
    }
}

// Legacy fp32 offset conv (fallback path only)
__global__ __launch_bounds__(256) void dcn_off_kernel(
    const float* __restrict__ x, const float* __restrict__ w,
    const float* __restrict__ bias, float* __restrict__ om,
    int r0, int rows)
{
    int b = blockIdx.x / rows;
    int rr = blockIdx.x % rows;
    int cw = threadIdx.x;
    int h = r0 + rr;
    int oc0 = blockIdx.y*24;
    const float* xb = x + (size_t)b*CH*HWSZ;
    float* omb = om + (size_t)b*216*rows*WW;
    float acc[24];
    #pragma unroll
    for (int j=0;j<24;++j) acc[j] = bias[oc0+j];
    for (int c=0;c<32;++c) {
        const float* xp = xb + (size_t)c*HWSZ;
        float v[9];
        #pragma unroll
        for (int t=0;t<9;++t) {
            int hh = h + t/3 - 1;
            int wx = cw + t%3 - 1;
            v[t] = (hh>=0 && hh<HH && wx>=0 && wx<WW) ? xp[hh*WW+wx] : 0.f;
        }
        const float* wpp = w + (size_t)c*9;
        #pragma unroll
        for (int j=0;j<24;++j) {
            #pragma unroll
            for (int t=0;t<9;++t)
                acc[j] += wpp[(size_t)(oc0+j)*288 + t] * v[t];
        }
    }
    #pragma unroll
    for (int j=0;j<24;++j)
        omb[(size_t)(oc0+j)*rows*WW + (size_t)rr*WW + cw] = acc[j];
}

// DCNv2 sampling + einsum + bias + lrelu (R9 proven shape: wave-uniform
// scalar addressing, 2 slices of 16 out-chans, grid (rows, 2, nb)).
__global__ __launch_bounds__(256) void dcn_kernel(
    const float* __restrict__ x, const float* __restrict__ om,
    const float* __restrict__ w, const float* __restrict__ bias,
    float* __restrict__ y, int r0, int rows)
{
    const int b  = blockIdx.z;
    const int os = blockIdx.y;
    const int rowsWW = rows*WW;
    int rr = blockIdx.x;
    int cw = threadIdx.x;
    int h = r0 + rr;
    const float* xb  = x  + (size_t)b*CH*HWSZ;
    const float* omb = om + (size_t)b*216*rowsWW;
    int ppos = rr*WW + cw;
    int ob = os*16;

    float acc[16];
    #pragma unroll
    for (int o=0;o<16;++o) acc[o] = bias[ob+o];

    for (int g=0; g<8; ++g) {
        const float* xg = xb + (size_t)g*4*HWSZ;
        #pragma unroll
        for (int k=0;k<9;++k) {
            int oc = g*9+k;
            const float* p_dy = omb + (size_t)oc*rowsWW;
            const float* p_dx = omb + (size_t)(72+oc)*rowsWW;
            const float* p_mm = omb + (size_t)(144+oc)*rowsWW;
            float dy = p_dy[ppos];
            float dx = p_dx[ppos];
            float mm = p_mm[ppos];
            mm = 1.f/(1.f + __expf(-mm));
            float py = dy + (float)(h + k/3 - 1);
            float px = dx + (float)(cw + k%3 - 1);
            float y0f = floorf(py), x0f = floorf(px);
            int yi = (int)y0f, xi = (int)x0f;
            float ty = py - y0f, tx = px - x0f;
            float w00 = (1.f-ty)*(1.f-tx), w01 = (1.f-ty)*tx;
            float w10 = ty*(1.f-tx),       w11 = ty*tx;
            int yc0 = min(max(yi,0),HH-1),   yc1 = min(max(yi+1,0),HH-1);
            int xc0 = min(max(xi,0),WW-1),   xc1 = min(max(xi+1,0),WW-1);
            bool vy0 = (yi>=0)&&(yi<HH),     vy1 = (yi+1>=0)&&(yi+1<HH);
            bool vx0 = (xi>=0)&&(xi<WW),     vx1 = (xi+1>=0)&&(xi+1<WW);
            float f00 = (vy0&&vx0)? w00*mm : 0.f;
            float f01 = (vy0&&vx1)? w01*mm : 0.f;
            float f10 = (vy1&&vx0)? w10*mm : 0.f;
            float f11 = (vy1&&vx1)? w11*mm : 0.f;
            int i00 = yc0*WW+xc0, i01 = yc0*WW+xc1;
            int i10 = yc1*WW+xc0, i11 = yc1*WW+xc1;
            #pragma unroll
            for (int c=0;c<4;++c) {
                const float* xc = xg + (size_t)c*HWSZ;
                float val = xc[i00]*f00 + xc[i01]*f01 + xc[i10]*f10 + xc[i11]*f11;
                const float* wpp = w + (size_t)(g*4+c)*9 + k;
                #pragma unroll
                for (int o=0;o<16;++o)
                    acc[o] += wpp[(size_t)(ob+o)*288] * val;
            }
        }
    }

    float* yb = y + (size_t)(b*CH + ob)*HWSZ + (size_t)h*WW;
    #pragma unroll
    for (int o=0;o<16;++o)
        yb[(size_t)o*HWSZ + cw] = lrelu_f(acc[o]);
}

extern "C" void kernel_launch(void* const* d_in, const int* in_sizes, int n_in,
                              void* d_out, int out_size, void* d_ws, size_t ws_size,
                              hipStream_t stream)
{
    (void)in_sizes; (void)n_in; (void)out_size;
    const float* short_fea = (const float*)d_in[0];
    const float* long_fea  = (const float*)d_in[1];
    const float* prev      = (const float*)d_in[2];
    const float* conv1_w   = (const float*)d_in[3];
    const float* conv1_b   = (const float*)d_in[4];
    const float* oc1_w     = (const float*)d_in[5];
    const float* oc1_b     = (const float*)d_in[6];
    const float* oc2_w     = (const float*)d_in[7];
    const float* oc2_b     = (const float*)d_in[8];
    const float* oc3_w     = (const float*)d_in[9];
    const float* oc3_b     = (const float*)d_in[10];
    const float* dow       = (const float*)d_in[11];
    const float* dob       = (const float*)d_in[12];
    const float* dcw       = (const float*)d_in[13];
    const float* dcb       = (const float*)d_in[14];

    float* out = (float*)d_out;                       // [2,32,256,256]
    float* off_out = out + (size_t)2*CH*HWSZ;         // [2,32,256,256]

    const int PIX_BLOCKS = (2*HWSZ)/256;   // 512

    // ws carve: om [2*216*HWSZ] f32 (bufB/bufU overlap it temporally),
    // then xq [2*HWSZ*32] bf16, then wpack [8064*8] bf16.
    size_t om_f   = (size_t)2*216*HWSZ;
    size_t xq_u   = (size_t)2*HWSZ*32;
    size_t wpk_u  = (size_t)9*14*64*8;
    size_t needed = om_f*4 + xq_u*2 + wpk_u*2;

    if (ws_size >= needed) {
        float* om  = (float*)d_ws;
        float* bufB = om;                              // lifetime: oc1..oc2
        float* bufU = om + (size_t)2*CH*HWSZ;          // lifetime: up2..oc2
        unsigned short* xq  = (unsigned short*)(om + om_f);
        unsigned short* wpk = xq + xq_u;

        conv1x1_kernel<<<PIX_BLOCKS, 256, 0, stream>>>(short_fea, long_fea, conv1_w, conv1_b, out);
        conv3x3_kernel<1><<<PIX_BLOCKS, 256, 0, stream>>>(out, nullptr, oc1_w, oc1_b, bufB, 1);
        up2_kernel<<<(2*CH*HWSZ)/256, 256, 0, stream>>>(prev, bufU);
        conv3x3_kernel<2><<<PIX_BLOCKS, 256, 0, stream>>>(bufB, bufU, oc2_w, oc2_b, out, 1);
        conv3x3_kernel<1><<<PIX_BLOCKS, 256, 0, stream>>>(out, nullptr, oc3_w, oc3_b, off_out, 1);

        pack_w_bf16<<<32, 256, 0, stream>>>(dow, wpk);
        nchw2nhwc_bf16<<<PIX_BLOCKS, 256, 0, stream>>>(off_out, xq);
        dcn_off_mfma<<<2*HH*4, 256, 0, stream>>>(xq, wpk, dob, om);

        dim3 g2(HH, 2, 2);
        dcn_kernel<<<g2, 256, 0, stream>>>(long_fea, om, dcw, dcb, out, 0, HH);
    } else {
        // Fallback: fp32 chunked path.
        float* bufB = (float*)d_ws;
        float* bufU = bufB + (size_t)2*CH*HWSZ;
        float* om   = bufU + (size_t)2*CH*HWSZ;
        size_t used = (size_t)2 * 2*CH*HWSZ * sizeof(float);
        size_t avail = (ws_size > used) ? (ws_size - used) : 0;

        conv1x1_kernel<<<PIX_BLOCKS, 256, 0, stream>>>(short_fea, long_fea, conv1_w, conv1_b, out);
        conv3x3_kernel<1><<<PIX_BLOCKS, 256, 0, stream>>>(out, nullptr, oc1_w, oc1_b, bufB, 1);
        up2_kernel<<<(2*CH*HWSZ)/256, 256, 0, stream>>>(prev, bufU);
        conv3x3_kernel<2><<<PIX_BLOCKS, 256, 0, stream>>>(bufB, bufU, oc2_w, oc2_b, out, 1);
        conv3x3_kernel<1><<<PIX_BLOCKS, 256, 0, stream>>>(out, nullptr, oc3_w, oc3_b, off_out, 1);

        size_t per_row = (size_t)216 * WW * sizeof(float);
        int rows_chunk = (int)(avail / per_row);
        if (rows_chunk < 1) rows_chunk = 1;
        if (rows_chunk > HH) rows_chunk = HH;
        for (int b=0;b<2;++b) {
            const float* offb = off_out + (size_t)b*CH*HWSZ;
            const float* lfb  = long_fea + (size_t)b*CH*HWSZ;
            float* outb = out + (size_t)b*CH*HWSZ;
            for (int r0=0;r0<HH;r0+=rows_chunk) {
                int rows = (HH - r0 < rows_chunk) ? (HH - r0) : rows_chunk;
                dim3 g1(rows, 9);
                dcn_off_kernel<<<g1, 256, 0, stream>>>(offb, dow, dob, om, r0, rows);
                dim3 g2f(rows, 2, 1);
                dcn_kernel<<<g2f, 256, 0, stream>>>(lfb, om, dcw, dcb, outb, r0, rows);
            }
        }
    }
}

// Round 11
// 520.169 us; speedup vs baseline: 4.1691x; 1.2139x over previous
//
#include <hip/hip_runtime.h>

#define HH 256
#define WW 256
#define HWSZ (HH*WW)
#define CH 32

typedef __attribute__((ext_vector_type(8))) short bfrag;   // 8 bf16 = 4 VGPRs
typedef __attribute__((ext_vector_type(4))) float f32x4;

__device__ __forceinline__ float lrelu_f(float x){ return x >= 0.f ? x : 0.2f*x; }

__device__ __forceinline__ unsigned short bf16_rne(float f){
    unsigned int u = __float_as_uint(f);
    unsigned int r = (u + 0x7fffu + ((u >> 16) & 1u)) >> 16;
    return (unsigned short)r;
}
__device__ __forceinline__ float bf16_to_f(unsigned short h){
    return __uint_as_float(((unsigned int)h) << 16);
}

// ============================ fp32 fallback kernels =========================

__global__ __launch_bounds__(256) void conv1x1_kernel(
    const float* __restrict__ s, const float* __restrict__ l,
    const float* __restrict__ w, const float* __restrict__ bias,
    float* __restrict__ y)
{
    int gid = blockIdx.x*256 + threadIdx.x;
    int b = gid >> 16;
    int pix = gid & (HWSZ-1);
    const float* sp = s + (size_t)b*CH*HWSZ + pix;
    const float* lp = l + (size_t)b*CH*HWSZ + pix;
    float acc[CH];
    #pragma unroll
    for (int o=0;o<CH;++o) acc[o] = bias[o];
    for (int c=0;c<CH;++c) {
        float v = sp[(size_t)c*HWSZ];
        #pragma unroll
        for (int o=0;o<CH;++o) acc[o] += w[o*64+c]*v;
    }
    for (int c=0;c<CH;++c) {
        float v = lp[(size_t)c*HWSZ];
        #pragma unroll
        for (int o=0;o<CH;++o) acc[o] += w[o*64+32+c]*v;
    }
    float* yp = y + (size_t)b*CH*HWSZ + pix;
    #pragma unroll
    for (int o=0;o<CH;++o) yp[(size_t)o*HWSZ] = acc[o];
}

template<int NP>
__global__ __launch_bounds__(256) void conv3x3_kernel(
    const float* __restrict__ x0, const float* __restrict__ x1,
    const float* __restrict__ w, const float* __restrict__ bias,
    float* __restrict__ y, int relu)
{
    int gid = blockIdx.x*256 + threadIdx.x;
    int b = gid >> 16;
    int pix = gid & (HWSZ-1);
    int h = pix >> 8, cw = pix & 255;
    const int CIN = 32*NP;
    float acc[CH];
    #pragma unroll
    for (int o=0;o<CH;++o) acc[o] = bias[o];
    #pragma unroll
    for (int p=0;p<NP;++p) {
        const float* src = (p==0) ? x0 : x1;
        const float* xb = src + (size_t)b*CH*HWSZ;
        for (int c=0;c<CH;++c) {
            const float* xp = xb + (size_t)c*HWSZ;
            float v[9];
            #pragma unroll
            for (int t=0;t<9;++t) {
                int hh = h + t/3 - 1;
                int wx = cw + t%3 - 1;
                v[t] = (hh>=0 && hh<HH && wx>=0 && wx<WW) ? xp[hh*WW+wx] : 0.f;
            }
            const float* wp = w + (size_t)(p*32 + c)*9;
            #pragma unroll
            for (int o=0;o<CH;++o) {
                #pragma unroll
                for (int t=0;t<9;++t)
                    acc[o] += wp[(size_t)o*CIN*9 + t] * v[t];
            }
        }
    }
    float* yp = y + (size_t)b*CH*HWSZ + pix;
    #pragma unroll
    for (int o=0;o<CH;++o)
        yp[(size_t)o*HWSZ] = relu ? lrelu_f(acc[o]) : acc[o];
}

__global__ __launch_bounds__(256) void up2_kernel(
    const float* __restrict__ x, float* __restrict__ y)
{
    int gid = blockIdx.x*256 + threadIdx.x;
    int ow = gid & 255;
    int oh = (gid >> 8) & 255;
    int bc = gid >> 16;
    const int Hin = 128, Win = 128;
    float cy = (oh + 0.5f)*0.5f - 0.5f;
    float cx = (ow + 0.5f)*0.5f - 0.5f;
    cy = fminf(fmaxf(cy, 0.f), (float)(Hin-1));
    cx = fminf(fmaxf(cx, 0.f), (float)(Win-1));
    int y0 = (int)floorf(cy);
    int x0 = (int)floorf(cx);
    int y1 = min(y0+1, Hin-1);
    int x1 = min(x0+1, Win-1);
    float ty = cy - (float)y0, tx = cx - (float)x0;
    const float* xp = x + (size_t)bc*Hin*Win;
    float v00 = xp[y0*Win+x0], v01 = xp[y0*Win+x1];
    float v10 = xp[y1*Win+x0], v11 = xp[y1*Win+x1];
    float v = v00*(1.f-ty)*(1.f-tx) + v01*(1.f-ty)*tx + v10*ty*(1.f-tx) + v11*ty*tx;
    y[gid] = 2.0f*v;
}

__global__ __launch_bounds__(256) void dcn_off_kernel(
    const float* __restrict__ x, const float* __restrict__ w,
    const float* __restrict__ bias, float* __restrict__ om,
    int r0, int rows)
{
    int b = blockIdx.x / rows;
    int rr = blockIdx.x % rows;
    int cw = threadIdx.x;
    int h = r0 + rr;
    int oc0 = blockIdx.y*24;
    const float* xb = x + (size_t)b*CH*HWSZ;
    float* omb = om + (size_t)b*216*rows*WW;
    float acc[24];
    #pragma unroll
    for (int j=0;j<24;++j) acc[j] = bias[oc0+j];
    for (int c=0;c<32;++c) {
        const float* xp = xb + (size_t)c*HWSZ;
        float v[9];
        #pragma unroll
        for (int t=0;t<9;++t) {
            int hh = h + t/3 - 1;
            int wx = cw + t%3 - 1;
            v[t] = (hh>=0 && hh<HH && wx>=0 && wx<WW) ? xp[hh*WW+wx] : 0.f;
        }
        const float* wpp = w + (size_t)c*9;
        #pragma unroll
        for (int j=0;j<24;++j) {
            #pragma unroll
            for (int t=0;t<9;++t)
                acc[j] += wpp[(size_t)(oc0+j)*288 + t] * v[t];
        }
    }
    #pragma unroll
    for (int j=0;j<24;++j)
        omb[(size_t)(oc0+j)*rows*WW + (size_t)rr*WW + cw] = acc[j];
}

// ============================ bf16 MFMA path ================================

// Pack dcn_off weights (plain bf16): wp[ks][nt][l][j] = dow[oc][c][ks]
__global__ __launch_bounds__(256) void pack_w_bf16(
    const float* __restrict__ dow, unsigned short* __restrict__ wp)
{
    int gid = blockIdx.x*256 + threadIdx.x;   // 9*14*64
    if (gid >= 9*14*64) return;
    int l = gid & 63;
    int rest = gid >> 6;
    int nt = rest % 14;
    int ks = rest / 14;
    int oc = nt*16 + (l & 15);
    int c0 = 8*(l >> 4);
    unsigned short outv[8];
    #pragma unroll
    for (int j=0;j<8;++j) {
        float v = (oc < 216) ? dow[(size_t)oc*288 + (size_t)(c0+j)*9 + ks] : 0.f;
        outv[j] = bf16_rne(v);
    }
    unsigned short* dst = wp + (size_t)gid*8;
    #pragma unroll
    for (int j=0;j<8;++j) dst[j] = outv[j];
}

// Pack a Cout=32 conv weight (OIHW fp32) into hi/lo A-fragment order.
// wphi/wplo[((ks*F+f)*2+nt)*64+l][j] ; c = f*32 + (l>>4)*8 + j.
__global__ __launch_bounds__(256) void pack_conv_hl(
    const float* __restrict__ w, unsigned short* __restrict__ wphi,
    unsigned short* __restrict__ wplo, int TAPS, int F)
{
    int total = TAPS*F*2*64;
    int gid = blockIdx.x*256 + threadIdx.x;
    if (gid >= total) return;
    int l = gid & 63;
    int q = gid >> 6;
    int nt = q & 1;
    int p = q >> 1;
    int f = p % F;
    int ks = p / F;
    int oc = nt*16 + (l & 15);
    int CIN = F*32;
    unsigned short hv[8], lv[8];
    #pragma unroll
    for (int j=0;j<8;++j) {
        int c = f*32 + (l>>4)*8 + j;
        float v = w[(size_t)oc*CIN*TAPS + (size_t)c*TAPS + ks];
        unsigned short h = bf16_rne(v);
        hv[j] = h;
        lv[j] = bf16_rne(v - bf16_to_f(h));
    }
    unsigned short* dh = wphi + (size_t)gid*8;
    unsigned short* dl = wplo + (size_t)gid*8;
    #pragma unroll
    for (int j=0;j<8;++j) { dh[j] = hv[j]; dl[j] = lv[j]; }
}

// concat(short,long) NCHW fp32 -> cat0 [b][pix][128] (hi s0..31,l32..63 | lo +64)
__global__ __launch_bounds__(256) void cat_in_hl(
    const float* __restrict__ s, const float* __restrict__ l,
    unsigned short* __restrict__ xq)
{
    int gid = blockIdx.x*256 + threadIdx.x;   // nb*HWSZ
    int b = gid >> 16;
    int pix = gid & (HWSZ-1);
    unsigned short* op = xq + (size_t)gid*128;
    #pragma unroll
    for (int part=0; part<2; ++part) {
        const float* src = (part==0 ? s : l) + (size_t)b*CH*HWSZ + pix;
        #pragma unroll
        for (int cb=0; cb<4; ++cb) {
            unsigned short hv[8], lv[8];
            #pragma unroll
            for (int j=0;j<8;++j) {
                float v = src[(size_t)(cb*8+j)*HWSZ];
                unsigned short h = bf16_rne(v);
                hv[j] = h;
                lv[j] = bf16_rne(v - bf16_to_f(h));
            }
            *reinterpret_cast<uint4*>(op + part*32 + cb*8)      = *reinterpret_cast<uint4*>(hv);
            *reinterpret_cast<uint4*>(op + 64 + part*32 + cb*8) = *reinterpret_cast<uint4*>(lv);
        }
    }
}

// bilinear x2 upsample (*2.0) -> cat channels 32..63 (hi) / 96..127 (lo)
__global__ __launch_bounds__(256) void up2_hl(
    const float* __restrict__ x, unsigned short* __restrict__ xq)
{
    int gid = blockIdx.x*256 + threadIdx.x;   // nb*HWSZ
    int b = gid >> 16;
    int pix = gid & (HWSZ-1);
    int oh = pix >> 8, ow = pix & 255;
    const int Hin = 128, Win = 128;
    float cy = (oh + 0.5f)*0.5f - 0.5f;
    float cx = (ow + 0.5f)*0.5f - 0.5f;
    cy = fminf(fmaxf(cy, 0.f), (float)(Hin-1));
    cx = fminf(fmaxf(cx, 0.f), (float)(Win-1));
    int y0 = (int)floorf(cy);
    int x0 = (int)floorf(cx);
    int y1 = min(y0+1, Hin-1);
    int x1 = min(x0+1, Win-1);
    float ty = cy - (float)y0, tx = cx - (float)x0;
    float w00 = (1.f-ty)*(1.f-tx), w01 = (1.f-ty)*tx;
    float w10 = ty*(1.f-tx),       w11 = ty*tx;
    unsigned short* op = xq + (size_t)gid*128;
    const float* xb = x + (size_t)b*32*Hin*Win;
    #pragma unroll
    for (int cb=0; cb<4; ++cb) {
        unsigned short hv[8], lv[8];
        #pragma unroll
        for (int j=0;j<8;++j) {
            const float* xp = xb + (size_t)(cb*8+j)*Hin*Win;
            float v = 2.0f*(xp[y0*Win+x0]*w00 + xp[y0*Win+x1]*w01 +
                            xp[y1*Win+x0]*w10 + xp[y1*Win+x1]*w11);
            unsigned short h = bf16_rne(v);
            hv[j] = h;
            lv[j] = bf16_rne(v - bf16_to_f(h));
        }
        *reinterpret_cast<uint4*>(op + 32 + cb*8)      = *reinterpret_cast<uint4*>(hv);
        *reinterpret_cast<uint4*>(op + 96 + cb*8)      = *reinterpret_cast<uint4*>(lv);
    }
}

// Generic Cout=32 conv via MFMA with double-bf16 (hi/lo) inputs+weights.
// Input xq: [b][HWSZ][2*F*32] (hi frags at f*32, lo at F*32+f*32).
// acc += Whi*xhi + Whi*xlo + Wlo*xhi.   Per block: one h row quarter (64 px).
template<int TAPS, int F, bool RELU, bool NCHW_OUT, bool LO_OUT>
__global__ __launch_bounds__(256) void conv_mfma(
    const unsigned short* __restrict__ xq,
    const unsigned short* __restrict__ wphi,
    const unsigned short* __restrict__ wplo,
    const float* __restrict__ bias,
    unsigned short* __restrict__ yq, int ochs, int ohioff, int oloff,
    float* __restrict__ ynchw)
{
    int bid = blockIdx.x;               // nb*HH*4
    int wq = bid & 3;
    int h  = (bid >> 2) & 255;
    int b  = bid >> 10;
    int wv = threadIdx.x >> 6;
    int l  = threadIdx.x & 63;
    int w0 = wq*64 + wv*16;
    int lw = l & 15;
    int lq = l >> 4;
    const int CHS = 2*F*32;

    f32x4 acc[2];
    acc[0] = (f32x4){0.f,0.f,0.f,0.f};
    acc[1] = (f32x4){0.f,0.f,0.f,0.f};

    const unsigned short* xb = xq + (size_t)b*HWSZ*CHS;
    const bfrag zero = {0,0,0,0,0,0,0,0};

    #pragma unroll 1
    for (int ks=0; ks<TAPS; ++ks) {
        int dy = (TAPS==9) ? ks/3 - 1 : 0;
        int dx = (TAPS==9) ? ks%3 - 1 : 0;
        int hh = h + dy;
        if (hh < 0 || hh >= HH) continue;
        int wx = w0 + lw + dx;
        bool vw = (wx >= 0) && (wx < WW);
        int wxc = min(max(wx, 0), WW-1);
        const unsigned short* xp = xb + ((size_t)hh*WW + wxc)*CHS + lq*8;
        bfrag bh[F], bl[F];
        #pragma unroll
        for (int f=0;f<F;++f) {
            bh[f] = *reinterpret_cast<const bfrag*>(xp + f*32);
            bl[f] = *reinterpret_cast<const bfrag*>(xp + F*32 + f*32);
            bh[f] = vw ? bh[f] : zero;
            bl[f] = vw ? bl[f] : zero;
        }
        #pragma unroll
        for (int nt=0; nt<2; ++nt) {
            #pragma unroll
            for (int f=0;f<F;++f) {
                size_t widx = ((size_t)((ks*F + f)*2 + nt)*64 + l)*8;
                bfrag ah = *reinterpret_cast<const bfrag*>(wphi + widx);
                bfrag al = *reinterpret_cast<const bfrag*>(wplo + widx);
                acc[nt] = __builtin_amdgcn_mfma_f32_16x16x32_bf16(ah, bh[f], acc[nt], 0, 0, 0);
                acc[nt] = __builtin_amdgcn_mfma_f32_16x16x32_bf16(ah, bl[f], acc[nt], 0, 0, 0);
                acc[nt] = __builtin_amdgcn_mfma_f32_16x16x32_bf16(al, bh[f], acc[nt], 0, 0, 0);
            }
        }
    }

    int pw = w0 + lw;
    size_t pix = (size_t)h*WW + pw;
    #pragma unroll
    for (int nt=0; nt<2; ++nt) {
        float yv[4];
        #pragma unroll
        for (int i=0;i<4;++i) {
            int oc = nt*16 + lq*4 + i;
            float v = acc[nt][i] + bias[oc];
            yv[i] = RELU ? lrelu_f(v) : v;
        }
        // bf16 hi (and lo) NHWC store: 4 consecutive channels per lane
        unsigned short hv[4], lv[4];
        #pragma unroll
        for (int i=0;i<4;++i) {
            unsigned short hbits = bf16_rne(yv[i]);
            hv[i] = hbits;
            lv[i] = bf16_rne(yv[i] - bf16_to_f(hbits));
        }
        size_t obase = ((size_t)b*HWSZ + pix)*ochs + nt*16 + lq*4;
        *reinterpret_cast<ushort4*>(yq + obase + ohioff) = *reinterpret_cast<ushort4*>(hv);
        if (LO_OUT)
            *reinterpret_cast<ushort4*>(yq + obase + oloff) = *reinterpret_cast<ushort4*>(lv);
        if (NCHW_OUT) {
            #pragma unroll
            for (int i=0;i<4;++i) {
                int oc = nt*16 + lq*4 + i;
                ynchw[((size_t)(b*32 + oc))*HWSZ + pix] = yv[i];
            }
        }
    }
}

// 3x3 conv 32->216 via MFMA, bf16 (plain). rows-chunked om.
__global__ __launch_bounds__(256) void dcn_off_mfma(
    const unsigned short* __restrict__ xq,   // [nb,H,W,32] bf16 (hi)
    const unsigned short* __restrict__ wp,   // [9][14][64][8]
    const float* __restrict__ bias,
    float* __restrict__ om,                  // [nb][216][rows*WW]
    int r0, int rows)
{
    int bid = blockIdx.x;                    // nb*rows*4
    int wq = bid & 3;
    int rloc = (bid >> 2) % rows;
    int b  = (bid >> 2) / rows;
    int h  = r0 + rloc;
    int wv = threadIdx.x >> 6;
    int l  = threadIdx.x & 63;
    int w0 = wq*64 + wv*16;
    int lw = l & 15;
    int lq = l >> 4;

    f32x4 acc[14];
    #pragma unroll
    for (int t=0;t<14;++t) acc[t] = (f32x4){0.f,0.f,0.f,0.f};

    const unsigned short* xb = xq + (size_t)b*HWSZ*32;
    const bfrag zero = {0,0,0,0,0,0,0,0};

    #pragma unroll 1
    for (int ks=0; ks<9; ++ks) {
        int dy = ks/3 - 1, dx = ks%3 - 1;
        int hh = h + dy;
        if (hh < 0 || hh >= HH) continue;
        int wx = w0 + lw + dx;
        bool vw = (wx >= 0) && (wx < WW);
        int wxc = min(max(wx, 0), WW-1);
        const unsigned short* xp = xb + ((size_t)hh*WW + wxc)*32 + lq*8;
        bfrag bfr = *reinterpret_cast<const bfrag*>(xp);
        bfr = vw ? bfr : zero;
        const unsigned short* wks = wp + (size_t)ks*14*64*8;
        #pragma unroll
        for (int nt=0; nt<14; ++nt) {
            bfrag afr = *reinterpret_cast<const bfrag*>(wks + ((size_t)nt*64 + l)*8);
            acc[nt] = __builtin_amdgcn_mfma_f32_16x16x32_bf16(afr, bfr, acc[nt], 0, 0, 0);
        }
    }

    float* omb = om + (size_t)b*216*rows*WW;
    size_t pbase = (size_t)rloc*WW + w0 + lw;
    #pragma unroll
    for (int nt=0; nt<14; ++nt) {
        #pragma unroll
        for (int i=0;i<4;++i) {
            int oc = nt*16 + lq*4 + i;
            if (oc < 216)
                omb[(size_t)oc*rows*WW + pbase] = acc[nt][i] + bias[oc];
        }
    }
}

// DCNv2 sampling + einsum + bias + lrelu (R9 proven shape).
__global__ __launch_bounds__(256) void dcn_kernel(
    const float* __restrict__ x, const float* __restrict__ om,
    const float* __restrict__ w, const float* __restrict__ bias,
    float* __restrict__ y, int r0, int rows)
{
    const int b  = blockIdx.z;
    const int os = blockIdx.y;
    const int rowsWW = rows*WW;
    int rr = blockIdx.x;
    int cw = threadIdx.x;
    int h = r0 + rr;
    const float* xb  = x  + (size_t)b*CH*HWSZ;
    const float* omb = om + (size_t)b*216*rowsWW;
    int ppos = rr*WW + cw;
    int ob = os*16;

    float acc[16];
    #pragma unroll
    for (int o=0;o<16;++o) acc[o] = bias[ob+o];

    for (int g=0; g<8; ++g) {
        const float* xg = xb + (size_t)g*4*HWSZ;
        #pragma unroll
        for (int k=0;k<9;++k) {
            int oc = g*9+k;
            const float* p_dy = omb + (size_t)oc*rowsWW;
            const float* p_dx = omb + (size_t)(72+oc)*rowsWW;
            const float* p_mm = omb + (size_t)(144+oc)*rowsWW;
            float dy = p_dy[ppos];
            float dx = p_dx[ppos];
            float mm = p_mm[ppos];
            mm = 1.f/(1.f + __expf(-mm));
            float py = dy + (float)(h + k/3 - 1);
            float px = dx + (float)(cw + k%3 - 1);
            float y0f = floorf(py), x0f = floorf(px);
            int yi = (int)y0f, xi = (int)x0f;
            float ty = py - y0f, tx = px - x0f;
            float w00 = (1.f-ty)*(1.f-tx), w01 = (1.f-ty)*tx;
            float w10 = ty*(1.f-tx),       w11 = ty*tx;
            int yc0 = min(max(yi,0),HH-1),   yc1 = min(max(yi+1,0),HH-1);
            int xc0 = min(max(xi,0),WW-1),   xc1 = min(max(xi+1,0),WW-1);
            bool vy0 = (yi>=0)&&(yi<HH),     vy1 = (yi+1>=0)&&(yi+1<HH);
            bool vx0 = (xi>=0)&&(xi<WW),     vx1 = (xi+1>=0)&&(xi+1<WW);
            float f00 = (vy0&&vx0)? w00*mm : 0.f;
            float f01 = (vy0&&vx1)? w01*mm : 0.f;
            float f10 = (vy1&&vx0)? w10*mm : 0.f;
            float f11 = (vy1&&vx1)? w11*mm : 0.f;
            int i00 = yc0*WW+xc0, i01 = yc0*WW+xc1;
            int i10 = yc1*WW+xc0, i11 = yc1*WW+xc1;
            #pragma unroll
            for (int c=0;c<4;++c) {
                const float* xc = xg + (size_t)c*HWSZ;
                float val = xc[i00]*f00 + xc[i01]*f01 + xc[i10]*f10 + xc[i11]*f11;
                const float* wpp = w + (size_t)(g*4+c)*9 + k;
                #pragma unroll
                for (int o=0;o<16;++o)
                    acc[o] += wpp[(size_t)(ob+o)*288] * val;
            }
        }
    }

    float* yb = y + (size_t)(b*CH + ob)*HWSZ + (size_t)h*WW;
    #pragma unroll
    for (int o=0;o<16;++o)
        yb[(size_t)o*HWSZ + cw] = lrelu_f(acc[o]);
}

extern "C" void kernel_launch(void* const* d_in, const int* in_sizes, int n_in,
                              void* d_out, int out_size, void* d_ws, size_t ws_size,
                              hipStream_t stream)
{
    (void)in_sizes; (void)n_in; (void)out_size;
    const float* short_fea = (const float*)d_in[0];
    const float* long_fea  = (const float*)d_in[1];
    const float* prev      = (const float*)d_in[2];
    const float* conv1_w   = (const float*)d_in[3];
    const float* conv1_b   = (const float*)d_in[4];
    const float* oc1_w     = (const float*)d_in[5];
    const float* oc1_b     = (const float*)d_in[6];
    const float* oc2_w     = (const float*)d_in[7];
    const float* oc2_b     = (const float*)d_in[8];
    const float* oc3_w     = (const float*)d_in[9];
    const float* oc3_b     = (const float*)d_in[10];
    const float* dow       = (const float*)d_in[11];
    const float* dob       = (const float*)d_in[12];
    const float* dcw       = (const float*)d_in[13];
    const float* dcb       = (const float*)d_in[14];

    float* out = (float*)d_out;                       // [2,32,256,256]
    float* off_out = out + (size_t)2*CH*HWSZ;         // [2,32,256,256]

    const int ROWS = 128;                              // om row-chunk
    // ws carve (bytes):
    size_t om_b   = (size_t)2*216*ROWS*WW*4;           // 56.6 MB
    size_t cat_b  = (size_t)2*HWSZ*128*2;              // 33.6 MB
    size_t t_b    = (size_t)2*HWSZ*64*2;               // 16.8 MB (t0 / t2 shared)
    size_t xo_b   = (size_t)2*HWSZ*32*2;               // 8.4 MB
    size_t wpk_b  = (size_t)9*14*64*8*2;               // dcn_off pack
    size_t wc1_b  = (size_t)1*2*2*64*8*2;
    size_t wo1_b  = (size_t)9*1*2*64*8*2;
    size_t wo2_b  = (size_t)9*2*2*64*8*2;
    size_t wo3_b  = (size_t)9*1*2*64*8*2;
    size_t needed = om_b + cat_b + t_b + xo_b + wpk_b + 2*(wc1_b+wo1_b+wo2_b+wo3_b);

    if (ws_size >= needed) {
        char* p = (char*)d_ws;
        float* om = (float*)p;                 p += om_b;
        unsigned short* cat = (unsigned short*)p;  p += cat_b;
        unsigned short* tbuf = (unsigned short*)p; p += t_b;     // t0 then t2
        unsigned short* xqo = (unsigned short*)p;  p += xo_b;
        unsigned short* wpk = (unsigned short*)p;  p += wpk_b;
        unsigned short* w1h = (unsigned short*)p;  p += wc1_b;
        unsigned short* w1l = (unsigned short*)p;  p += wc1_b;
        unsigned short* wo1h = (unsigned short*)p; p += wo1_b;
        unsigned short* wo1l = (unsigned short*)p; p += wo1_b;
        unsigned short* wo2h = (unsigned short*)p; p += wo2_b;
        unsigned short* wo2l = (unsigned short*)p; p += wo2_b;
        unsigned short* wo3h = (unsigned short*)p; p += wo3_b;
        unsigned short* wo3l = (unsigned short*)p;

        // weight packs (tiny)
        pack_conv_hl<<<1, 256, 0, stream>>>(conv1_w, w1h, w1l, 1, 2);
        pack_conv_hl<<<5, 256, 0, stream>>>(oc1_w, wo1h, wo1l, 9, 1);
        pack_conv_hl<<<9, 256, 0, stream>>>(oc2_w, wo2h, wo2l, 9, 2);
        pack_conv_hl<<<5, 256, 0, stream>>>(oc3_w, wo3h, wo3l, 9, 1);
        pack_w_bf16<<<32, 256, 0, stream>>>(dow, wpk);

        const int PIX_BLOCKS = (2*HWSZ)/256;   // 512
        const int CONV_BLOCKS = 2*HH*4;        // 2048

        // conv1 (1x1, no act): cat0(hi/lo of concat) -> t0
        cat_in_hl<<<PIX_BLOCKS, 256, 0, stream>>>(short_fea, long_fea, cat);
        conv_mfma<1,2,false,false,true><<<CONV_BLOCKS, 256, 0, stream>>>(
            cat, w1h, w1l, conv1_b, tbuf, 64, 0, 32, nullptr);
        // oc1 (lrelu): t0 -> cat[0..31 | 64..95]
        conv_mfma<9,1,true,false,true><<<CONV_BLOCKS, 256, 0, stream>>>(
            tbuf, wo1h, wo1l, oc1_b, cat, 128, 0, 64, nullptr);
        // up2 (*2): prev -> cat[32..63 | 96..127]
        up2_hl<<<PIX_BLOCKS, 256, 0, stream>>>(prev, cat);
        // oc2 (lrelu): cat -> t2
        conv_mfma<9,2,true,false,true><<<CONV_BLOCKS, 256, 0, stream>>>(
            cat, wo2h, wo2l, oc2_b, tbuf, 64, 0, 32, nullptr);
        // oc3 (lrelu): t2 -> off_out (fp32 NCHW, output #2) + xqo (bf16 hi)
        conv_mfma<9,1,true,true,false><<<CONV_BLOCKS, 256, 0, stream>>>(
            tbuf, wo3h, wo3l, oc3_b, xqo, 32, 0, 0, off_out);

        // DCN: offset conv + sampling, row-chunked
        for (int r0 = 0; r0 < HH; r0 += ROWS) {
            dcn_off_mfma<<<2*ROWS*4, 256, 0, stream>>>(xqo, wpk, dob, om, r0, ROWS);
            dim3 g2(ROWS, 2, 2);
            dcn_kernel<<<g2, 256, 0, stream>>>(long_fea, om, dcw, dcb, out, r0, ROWS);
        }
    } else {
        // fp32 fallback
        float* bufB = (float*)d_ws;
        float* bufU = bufB + (size_t)2*CH*HWSZ;
        float* om   = bufU + (size_t)2*CH*HWSZ;
        size_t used = (size_t)2 * 2*CH*HWSZ * sizeof(float);
        size_t avail = (ws_size > used) ? (ws_size - used) : 0;
        const int PIX_BLOCKS = (2*HWSZ)/256;

        conv1x1_kernel<<<PIX_BLOCKS, 256, 0, stream>>>(short_fea, long_fea, conv1_w, conv1_b, out);
        conv3x3_kernel<1><<<PIX_BLOCKS, 256, 0, stream>>>(out, nullptr, oc1_w, oc1_b, bufB, 1);
        up2_kernel<<<(2*CH*HWSZ)/256, 256, 0, stream>>>(prev, bufU);
        conv3x3_kernel<2><<<PIX_BLOCKS, 256, 0, stream>>>(bufB, bufU, oc2_w, oc2_b, out, 1);
        conv3x3_kernel<1><<<PIX_BLOCKS, 256, 0, stream>>>(out, nullptr, oc3_w, oc3_b, off_out, 1);

        size_t per_row = (size_t)216 * WW * sizeof(float);
        int rows_chunk = (int)(avail / per_row);
        if (rows_chunk < 1) rows_chunk = 1;
        if (rows_chunk > HH) rows_chunk = HH;
        for (int b=0;b<2;++b) {
            const float* offb = off_out + (size_t)b*CH*HWSZ;
            const float* lfb  = long_fea + (size_t)b*CH*HWSZ;
            float* outb = out + (size_t)b*CH*HWSZ;
            for (int r0=0;r0<HH;r0+=rows_chunk) {
                int rows = (HH - r0 < rows_chunk) ? (HH - r0) : rows_chunk;
                dim3 g1(rows, 9);
                dcn_off_kernel<<<g1, 256, 0, stream>>>(offb, dow, dob, om, r0, rows);
                dim3 g2f(rows, 2, 1);
                dcn_kernel<<<g2f, 256, 0, stream>>>(lfb, om, dcw, dcb, outb, r0, rows);
            }
        }
    }
}